// Round 7
// baseline (527.027 us; speedup 1.0000x reference)
//
#include <hip/hip_runtime.h>
#include <math.h>

#pragma clang fp contract(off)

typedef unsigned long long ull;

#define NCLS 80
#define NTOT 3800
#define CAND_CAP 4096
#define NMS_CAP 1024
#define CLS_CAP 128
// fast-score hist over float-bits [0.5, 1.0): 1024 bins of 2^13 ULP
#define BIN_LO 0x3F000000u
#define NB 1024
#define BSHIFT 13
#define QPB 1024
#define NBLK 1044
#define PBUF_CAP 320
#define GCAP 16384
#define ZWORDS 6496   // tot(5120) + gcnt(80) + clscnt(1280) + lvlbad(16)

__constant__ int d_BSQ[6]  = {0, 782, 978, 1027, 1040, 1044};
__constant__ int d_QL[5]   = {800000, 200000, 50000, 12800, 3200};
__constant__ int d_EL[5]   = {3200000, 800000, 200000, 51200, 12800};
__constant__ float d_PREHI[5] = {0.86f, 0.82f, 0.78f, 0.74f, 0.74f};
__constant__ int d_KL[5] = {1000,1000,1000,640,160};
__constant__ int d_OB[5] = {0,1000,2000,3000,3640};

struct Params {
  const float *cls0,*cls1,*cls2,*cls3,*cls4;
  const float *ctn0,*ctn1,*ctn2,*ctn3,*ctn4;
  const float *box0,*box1,*box2,*box3,*box4;
  const int* img;
  unsigned* tot;             // 5*NB (zero region start)
  unsigned* gcnt;            // 5 x stride16
  unsigned* clscnt;          // 80 x stride16
  unsigned* lvlbad;          // 5 (padded 16)
  ull* gcand;                // 5*GCAP exact-score candidates
  ull* clskey;               // 80*CLS_CAP
  unsigned* slot_bits;       // NTOT
  unsigned* slot_label;      // NTOT
  float* slot_box;           // NTOT*4
  float* out;                // 26600 floats
};

__device__ __forceinline__ float fast_sig(float x) {
  return 1.0f / (1.0f + __expf(-x));
}
__device__ __forceinline__ float fast_score(float c, float t) {
  return sqrtf(fast_sig(c) * fast_sig(t));
}
// exact: emulate ref f32 pipeline with correctly-rounded expf (f64 exp -> f32)
__device__ __forceinline__ float sigmoid_ref(float x) {
  float e = (float)exp(-(double)x);
  return 1.0f / (1.0f + e);
}
__device__ __forceinline__ float score_ref(float c, float t) {
  return sqrtf(sigmoid_ref(c) * sigmoid_ref(t));
}
__device__ __forceinline__ float iou_ref(float ax1,float ay1,float ax2,float ay2,
                                         float bx1,float by1,float bx2,float by2) {
  float areaA = fmaxf(ax2-ax1,0.0f) * fmaxf(ay2-ay1,0.0f);
  float areaB = fmaxf(bx2-bx1,0.0f) * fmaxf(by2-by1,0.0f);
  float ix1 = fmaxf(ax1,bx1), iy1 = fmaxf(ay1,by1);
  float ix2 = fminf(ax2,bx2), iy2 = fminf(ay2,by2);
  float inter = fmaxf(ix2-ix1,0.0f) * fmaxf(iy2-iy1,0.0f);
  float uni = areaA + areaB - inter;
  return inter / fmaxf(uni, 1e-9f);
}
__device__ __forceinline__ const float* cls_of(const Params& p, int l) {
  return (l==0)?p.cls0:(l==1)?p.cls1:(l==2)?p.cls2:(l==3)?p.cls3:p.cls4;
}
__device__ __forceinline__ const float* ctn_of(const Params& p, int l) {
  return (l==0)?p.ctn0:(l==1)?p.ctn1:(l==2)?p.ctn2:(l==3)?p.ctn3:p.ctn4;
}
__device__ __forceinline__ const float* box_of(const Params& p, int l) {
  return (l==0)?p.box0:(l==1)?p.box1:(l==2)?p.box2:(l==3)?p.box3:p.box4;
}

__global__ __launch_bounds__(256) void k_zero(unsigned* z) {
  for (int i = blockIdx.x*256 + threadIdx.x; i < ZWORDS; i += 256) z[i] = 0u;
}

// Pass 1: fast scores; hits (fast >= PREHI) get exact f64 rescore in-registers,
// global hist atomics (hits only), and block-compacted append to gcand.
__global__ __launch_bounds__(256) void k_score(Params p) {
  int b = blockIdx.x, tid = threadIdx.x;
  __shared__ ull pbuf[PBUF_CAP];
  __shared__ unsigned pcnt;
  __shared__ unsigned base_sh;
  if (tid == 0) pcnt = 0u;
  __syncthreads();
  int l = 0;
  while (b >= d_BSQ[l+1]) ++l;
  int cb = b - d_BSQ[l];
  int q0 = cb * QPB;
  int nq = d_QL[l] - q0; if (nq > QPB) nq = QPB;
  const float* cls = cls_of(p, l);
  const float* ctn = ctn_of(p, l);
  float prehi = d_PREHI[l];
  unsigned* tl = p.tot + l*NB;
  for (int i = tid; i < nq; i += 256) {
    int q = q0 + i;
    float4 c4 = ((const float4*)cls)[q];
    float ct = ctn[q / 20];               // anchor = (4q)/80
    float st = fast_sig(ct);
    float cv[4] = {c4.x, c4.y, c4.z, c4.w};
    #pragma unroll
    for (int j = 0; j < 4; ++j) {
      float s = sqrtf(fast_sig(cv[j]) * st);
      if (s >= prehi) {
        unsigned fb = __float_as_uint(s);
        unsigned bin = (fb - BIN_LO) >> BSHIFT;
        if (bin > NB-1) bin = NB-1;
        atomicAdd(&tl[bin], 1u);
        float ex = score_ref(cv[j], ct);  // exact, from registers
        unsigned pos = atomicAdd(&pcnt, 1u);
        if (pos < PBUF_CAP)
          pbuf[pos] = ((ull)__float_as_uint(ex) << 32)
                    | (ull)(0xFFFFFFFFu - (unsigned)(4*q + j));
      }
    }
  }
  __syncthreads();
  unsigned n = pcnt;
  if (n > PBUF_CAP) { if (tid == 0) p.lvlbad[l] = 1u; n = PBUF_CAP; }
  if (tid == 0) base_sh = atomicAdd(&p.gcnt[l*16], n);
  __syncthreads();
  unsigned base = base_sh;
  ull* gc = p.gcand + (size_t)l * GCAP;
  for (unsigned i = tid; i < n; i += 256) {
    unsigned d = base + i;
    if (d < GCAP) gc[d] = pbuf[i];
    else p.lvlbad[l] = 1u;
  }
}

// Rank: 64 slice-waves per level. Each wave: in-wave thr search, deterministic
// ballot-compacted re-filter of gcand (same key order in every block), then
// ranks its 64-slice and emits labels/boxes/slots + class lists.
__global__ __launch_bounds__(64) void k_rank(Params p) {
  int bx = blockIdx.x;
  int l = bx >> 6, slice = bx & 63;
  int lane = threadIdx.x;
  __shared__ unsigned hist[NB];
  __shared__ ull key[CAND_CAP];
  for (int j = 0; j < NB/64; ++j)
    hist[lane + j*64] = p.tot[l*NB + lane + j*64];
  __syncthreads();
  // chunked threshold search: lane j covers bins [1008-16j, 1024-16j)
  int chunkbase = 1008 - 16*lane;
  unsigned csum = 0;
  #pragma unroll
  for (int t = 0; t < 16; ++t) csum += hist[chunkbase + t];
  unsigned cum = csum;
  for (int d = 1; d < 64; d <<= 1) {
    unsigned tu = __shfl_up(cum, d);
    if (lane >= d) cum += tu;
  }
  unsigned k = (unsigned)d_KL[l];
  ull okm = __ballot(cum >= k);
  unsigned thr = BIN_LO;
  if (okm) {
    int j0 = (int)__ffsll((long long)okm) - 1;
    if (lane == j0) {
      unsigned acc = cum - csum;
      int cb2 = 1008 - 16*j0;
      for (int bb = cb2 + 15; bb >= cb2; --bb) {
        acc += hist[bb];
        if (acc >= k) {
          if (bb > 0) thr = BIN_LO + ((unsigned)(bb - 1) << BSHIFT);  // 1-bin safety
          break;
        }
      }
    }
    thr = __shfl(thr, j0);
  }
  bool fastok = (p.lvlbad[l] == 0u) && (thr >= __float_as_uint(d_PREHI[l]));
  int m = 0;
  if (fastok) {
    int gn = (int)p.gcnt[l*16]; if (gn > GCAP) gn = GCAP;
    const ull* gc = p.gcand + (size_t)l * GCAP;
    for (int i0 = 0; i0 < gn; i0 += 64) {
      int i = i0 + lane;
      ull kk = (i < gn) ? gc[i] : 0ULL;
      bool pred = (i < gn) && ((unsigned)(kk >> 32) >= thr);
      ull mask = __ballot(pred);
      if (pred) {
        int pos = m + (int)__popcll(mask & ((1ULL << lane) - 1ULL));
        if (pos < CAND_CAP) key[pos] = kk;
      }
      m += (int)__popcll(mask);
    }
  } else {
    // fallback: deterministic full-level rescan (statistically unreachable)
    int ne = d_EL[l];
    const float* cls = cls_of(p, l);
    const float* ctn = ctn_of(p, l);
    for (int i0 = 0; i0 < ne; i0 += 64) {
      int i = i0 + lane;
      bool pred = false; ull kk = 0ULL;
      if (i < ne) {
        float fs = fast_score(cls[i], ctn[i / NCLS]);
        if (__float_as_uint(fs) >= thr) {
          float ex = score_ref(cls[i], ctn[i / NCLS]);
          kk = ((ull)__float_as_uint(ex) << 32) | (ull)(0xFFFFFFFFu - (unsigned)i);
          pred = true;
        }
      }
      ull mask = __ballot(pred);
      if (pred) {
        int pos = m + (int)__popcll(mask & ((1ULL << lane) - 1ULL));
        if (pos < CAND_CAP) key[pos] = kk;
      }
      m += (int)__popcll(mask);
    }
  }
  if (m > CAND_CAP) m = CAND_CAP;
  __syncthreads();
  int kL = d_KL[l], obase = d_OB[l];
  int i = slice*64 + lane;
  if (i >= m) {
    if (i < kL) {   // defensive fill (m >= kL in practice; out is poisoned)
      int g = obase + i;
      p.out[g] = 0.0f;
      p.out[NTOT + g] = 0.0f;
      ((float4*)(p.out + 2*NTOT))[g] = make_float4(0,0,0,0);
      p.out[6*NTOT + g] = 0.0f;
      ((float4*)p.slot_box)[g] = make_float4(0,0,0,0);
      p.slot_bits[g] = 0u;
      p.slot_label[g] = 0xFFFFFFFFu;
    }
    return;
  }
  ull mine = key[i];
  int rank = 0;
  int mm = m & ~7;
  #pragma unroll 1
  for (int j = 0; j < mm; j += 8) {
    rank += (key[j  ] > mine) + (key[j+1] > mine) + (key[j+2] > mine) + (key[j+3] > mine)
          + (key[j+4] > mine) + (key[j+5] > mine) + (key[j+6] > mine) + (key[j+7] > mine);
  }
  for (int j = mm; j < m; ++j) rank += (key[j] > mine) ? 1 : 0;
  if (rank >= kL) return;
  int g = obase + rank;
  unsigned bits = (unsigned)(mine >> 32);
  unsigned fi = 0xFFFFFFFFu - (unsigned)(mine & 0xFFFFFFFFu);
  unsigned lab = fi % NCLS;
  unsigned a = fi / NCLS;
  float img = (float)(*p.img);
  float4 b4 = ((const float4*)box_of(p, l))[a];
  float4 nb;
  nb.x = fminf(fmaxf(b4.x / img, 0.0f), 1.0f);
  nb.y = fminf(fmaxf(b4.y / img, 0.0f), 1.0f);
  nb.z = fminf(fmaxf(b4.z / img, 0.0f), 1.0f);
  nb.w = fminf(fmaxf(b4.w / img, 0.0f), 1.0f);
  p.out[NTOT + g] = (float)lab;
  ((float4*)(p.out + 2*NTOT))[g] = nb;
  ((float4*)p.slot_box)[g] = b4;
  p.slot_bits[g] = bits;
  p.slot_label[g] = lab;
  unsigned pos = atomicAdd(&p.clscnt[lab*16], 1u);
  if (pos < CLS_CAP)
    p.clskey[lab*CLS_CAP + pos] = ((ull)bits << 32) | (ull)(0xFFFFFFFFu - (unsigned)g);
}

// Per-class NMS. m<=64: single-wave shfl/ballot path (no barriers).
__global__ __launch_bounds__(64) void k_nms(Params p) {
  int c = blockIdx.x, lane = threadIdx.x;
  int mc = (int)p.clscnt[c*16];
  if (mc == 0) return;
  if (mc <= 64) {
    ull kk = (lane < mc) ? p.clskey[c*CLS_CAP + lane] : 0ULL;
    int rank = 0;
    #pragma unroll 1
    for (int j = 0; j < 64; ++j) {
      ull kj = __shfl(kk, j);
      rank += (j < mc && kj > kk) ? 1 : 0;
    }
    __shared__ ull wkey[64];
    if (lane < mc) wkey[rank] = kk;
    __syncthreads();
    ull sk = (lane < mc) ? wkey[lane] : 0ULL;
    unsigned g = 0xFFFFFFFFu - (unsigned)(sk & 0xFFFFFFFFu);
    float s = __uint_as_float((unsigned)(sk >> 32));
    float off = 2.0f * (float)c;
    float x1=0,y1=0,x2=0,y2=0;
    if (lane < mc) {
      float4 b4 = ((const float4*)p.slot_box)[g];
      x1 = b4.x + off; y1 = b4.y + off; x2 = b4.z + off; y2 = b4.w + off;
    }
    ull keepm = __ballot(lane < mc && s > 0.05f);
    for (int i = 0; i + 1 < mc; ++i) {
      if ((keepm >> i) & 1ULL) {
        float ax1 = __shfl(x1, i), ay1 = __shfl(y1, i);
        float ax2 = __shfl(x2, i), ay2 = __shfl(y2, i);
        bool kept = (keepm >> lane) & 1ULL;
        bool sup = kept && (lane > i) && (lane < mc) &&
                   (iou_ref(ax1,ay1,ax2,ay2, x1,y1,x2,y2) > 0.6f);
        keepm &= ~__ballot(sup);
      }
    }
    if (lane < mc) {
      int kp = (int)((keepm >> lane) & 1ULL);
      p.out[g] = kp ? s : 0.0f;
      p.out[6*NTOT + g] = kp ? 1.0f : 0.0f;
    }
    return;
  }
  // LDS path (rare): 64<mc<=128 from clskey; mc>128 rebuild by scanning slots
  __shared__ ull key[NMS_CAP];
  __shared__ ull skey[NMS_CAP];
  __shared__ float bxs[NMS_CAP*4];
  __shared__ int keep[NMS_CAP];
  __shared__ unsigned mcnt_s;
  int m;
  if (mc <= CLS_CAP) {
    for (int j = lane; j < mc; j += 64) key[j] = p.clskey[c*CLS_CAP + j];
    m = mc;
    __syncthreads();
  } else {
    if (lane == 0) mcnt_s = 0u;
    __syncthreads();
    for (int g = lane; g < NTOT; g += 64) {
      if (p.slot_label[g] == (unsigned)c) {
        unsigned pos = atomicAdd(&mcnt_s, 1u);
        if (pos < NMS_CAP)
          key[pos] = ((ull)p.slot_bits[g] << 32) | (ull)(0xFFFFFFFFu - (unsigned)g);
      }
    }
    __syncthreads();
    m = (mcnt_s < NMS_CAP) ? (int)mcnt_s : NMS_CAP;
  }
  for (int i = lane; i < m; i += 64) {
    ull mine = key[i];
    int rank = 0;
    for (int j = 0; j < m; ++j) rank += (key[j] > mine) ? 1 : 0;
    skey[rank] = mine;
  }
  __syncthreads();
  float off = 2.0f * (float)c;
  for (int j = lane; j < m; j += 64) {
    ull kk = skey[j];
    unsigned g = 0xFFFFFFFFu - (unsigned)(kk & 0xFFFFFFFFu);
    for (int q = 0; q < 4; ++q) bxs[j*4+q] = p.slot_box[g*4+q] + off;
    float s = __uint_as_float((unsigned)(kk >> 32));
    keep[j] = (s > 0.05f) ? 1 : 0;
  }
  __syncthreads();
  for (int i = 0; i + 1 < m; ++i) {
    if (keep[i]) {
      float ax1 = bxs[i*4+0], ay1 = bxs[i*4+1], ax2 = bxs[i*4+2], ay2 = bxs[i*4+3];
      for (int j = i + 1 + lane; j < m; j += 64) {
        if (keep[j]) {
          if (iou_ref(ax1,ay1,ax2,ay2, bxs[j*4+0],bxs[j*4+1],bxs[j*4+2],bxs[j*4+3]) > 0.6f)
            keep[j] = 0;
        }
      }
    }
    __syncthreads();
  }
  for (int j = lane; j < m; j += 64) {
    ull kk = skey[j];
    unsigned g = 0xFFFFFFFFu - (unsigned)(kk & 0xFFFFFFFFu);
    float s = __uint_as_float((unsigned)(kk >> 32));
    int kp = keep[j];
    p.out[g] = kp ? s : 0.0f;
    p.out[6*NTOT + g] = kp ? 1.0f : 0.0f;
  }
}

extern "C" void kernel_launch(void* const* d_in, const int* in_sizes, int n_in,
                              void* d_out, int out_size, void* d_ws, size_t ws_size,
                              hipStream_t stream) {
  Params p;
  p.cls0 = (const float*)d_in[0];  p.ctn0 = (const float*)d_in[1];  p.box0 = (const float*)d_in[2];
  p.cls1 = (const float*)d_in[3];  p.ctn1 = (const float*)d_in[4];  p.box1 = (const float*)d_in[5];
  p.cls2 = (const float*)d_in[6];  p.ctn2 = (const float*)d_in[7];  p.box2 = (const float*)d_in[8];
  p.cls3 = (const float*)d_in[9];  p.ctn3 = (const float*)d_in[10]; p.box3 = (const float*)d_in[11];
  p.cls4 = (const float*)d_in[12]; p.ctn4 = (const float*)d_in[13]; p.box4 = (const float*)d_in[14];
  p.img  = (const int*)d_in[15];

  char* w = (char*)d_ws;
  // contiguous zero region: tot | gcnt | clscnt | lvlbad  (ZWORDS words)
  unsigned* zbase = (unsigned*)w;
  p.tot    = zbase;                       // 5*1024 = 5120 words
  p.gcnt   = zbase + 5120;                // 5 x stride16 = 80 words
  p.clscnt = zbase + 5120 + 80;           // 80 x stride16 = 1280 words
  p.lvlbad = zbase + 5120 + 80 + 1280;    // 16 words
  w += (size_t)ZWORDS*4;
  p.gcand = (ull*)w;           w += (size_t)5*GCAP*8;        // 655,360
  p.clskey = (ull*)w;          w += (size_t)NCLS*CLS_CAP*8;  // 81,920
  p.slot_bits  = (unsigned*)w; w += NTOT*4;
  p.slot_label = (unsigned*)w; w += NTOT*4;
  p.slot_box   = (float*)w;    w += NTOT*16;
  p.out = (float*)d_out;

  hipLaunchKernelGGL(k_zero,  dim3(1),    dim3(256), 0, stream, zbase);
  hipLaunchKernelGGL(k_score, dim3(NBLK), dim3(256), 0, stream, p);
  hipLaunchKernelGGL(k_rank,  dim3(5*64), dim3(64),  0, stream, p);
  hipLaunchKernelGGL(k_nms,   dim3(80),   dim3(64),  0, stream, p);
}

// Round 8
// 187.496 us; speedup vs baseline: 2.8109x; 2.8109x over previous
//
#include <hip/hip_runtime.h>
#include <math.h>

#pragma clang fp contract(off)

typedef unsigned long long ull;

#define NCLS 80
#define NTOT 3800
#define CAND_CAP 4096
#define NMS_CAP 1024
#define CLS_CAP 128
// fast-score hist over float-bits [0.5, 1.0): 1024 bins of 2^13 ULP
#define BIN_LO 0x3F000000u
#define NB 1024
#define BSHIFT 13
#define QPB 1024
#define NBLK 1044
#define PBUF_CAP 320
#define GCAP 65536
#define ZWORDS 6576   // tot(5120) + gcnt(80) + ccount(80) + clscnt(1280) + lvlbad(16)

__constant__ int d_BSQ[6]  = {0, 782, 978, 1027, 1040, 1044};
__constant__ int d_QL[5]   = {800000, 200000, 50000, 12800, 3200};
__constant__ int d_EL[5]   = {3200000, 800000, 200000, 51200, 12800};
__constant__ float d_PREHI[5] = {0.86f, 0.82f, 0.78f, 0.74f, 0.74f};
__constant__ int d_KL[5] = {1000,1000,1000,640,160};
__constant__ int d_OB[5] = {0,1000,2000,3000,3640};

struct Params {
  const float *cls0,*cls1,*cls2,*cls3,*cls4;
  const float *ctn0,*ctn1,*ctn2,*ctn3,*ctn4;
  const float *box0,*box1,*box2,*box3,*box4;
  const int* img;
  unsigned* tot;             // 5*NB (zero region start)
  unsigned* gcnt;            // 5 x stride16
  unsigned* ccount;          // 5 x stride16
  unsigned* clscnt;          // 80 x stride16
  unsigned* lvlbad;          // 5 (padded 16)
  ull* gcand;                // 5*GCAP exact-score prefilter candidates
  ull* ckey;                 // 5*CAND_CAP filtered keys
  ull* clskey;               // 80*CLS_CAP
  unsigned* slot_bits;       // NTOT
  unsigned* slot_label;      // NTOT
  float* slot_box;           // NTOT*4
  float* out;                // 26600 floats
};

__device__ __forceinline__ float fast_sig(float x) {
  return 1.0f / (1.0f + __expf(-x));
}
__device__ __forceinline__ float fast_score(float c, float t) {
  return sqrtf(fast_sig(c) * fast_sig(t));
}
// exact: emulate ref f32 pipeline with correctly-rounded expf (f64 exp -> f32)
__device__ __forceinline__ float sigmoid_ref(float x) {
  float e = (float)exp(-(double)x);
  return 1.0f / (1.0f + e);
}
__device__ __forceinline__ float score_ref(float c, float t) {
  return sqrtf(sigmoid_ref(c) * sigmoid_ref(t));
}
__device__ __forceinline__ float iou_ref(float ax1,float ay1,float ax2,float ay2,
                                         float bx1,float by1,float bx2,float by2) {
  float areaA = fmaxf(ax2-ax1,0.0f) * fmaxf(ay2-ay1,0.0f);
  float areaB = fmaxf(bx2-bx1,0.0f) * fmaxf(by2-by1,0.0f);
  float ix1 = fmaxf(ax1,bx1), iy1 = fmaxf(ay1,by1);
  float ix2 = fminf(ax2,bx2), iy2 = fminf(ay2,by2);
  float inter = fmaxf(ix2-ix1,0.0f) * fmaxf(iy2-iy1,0.0f);
  float uni = areaA + areaB - inter;
  return inter / fmaxf(uni, 1e-9f);
}
__device__ __forceinline__ const float* cls_of(const Params& p, int l) {
  return (l==0)?p.cls0:(l==1)?p.cls1:(l==2)?p.cls2:(l==3)?p.cls3:p.cls4;
}
__device__ __forceinline__ const float* ctn_of(const Params& p, int l) {
  return (l==0)?p.ctn0:(l==1)?p.ctn1:(l==2)?p.ctn2:(l==3)?p.ctn3:p.ctn4;
}
__device__ __forceinline__ const float* box_of(const Params& p, int l) {
  return (l==0)?p.box0:(l==1)?p.box1:(l==2)?p.box2:(l==3)?p.box3:p.box4;
}

__global__ __launch_bounds__(256) void k_zero(unsigned* z) {
  for (int i = blockIdx.x*256 + threadIdx.x; i < ZWORDS; i += 256) z[i] = 0u;
}

// Pass 1: fast scores; hits (fast >= PREHI) get exact f64 rescore in-registers,
// global hist atomics (hits only), block-compacted append to gcand.
__global__ __launch_bounds__(256) void k_score(Params p) {
  int b = blockIdx.x, tid = threadIdx.x;
  __shared__ ull pbuf[PBUF_CAP];
  __shared__ unsigned pcnt;
  __shared__ unsigned base_sh;
  if (tid == 0) pcnt = 0u;
  __syncthreads();
  int l = 0;
  while (b >= d_BSQ[l+1]) ++l;
  int cb = b - d_BSQ[l];
  int q0 = cb * QPB;
  int nq = d_QL[l] - q0; if (nq > QPB) nq = QPB;
  const float* cls = cls_of(p, l);
  const float* ctn = ctn_of(p, l);
  float prehi = d_PREHI[l];
  unsigned* tl = p.tot + l*NB;
  for (int i = tid; i < nq; i += 256) {
    int q = q0 + i;
    float4 c4 = ((const float4*)cls)[q];
    float ct = ctn[q / 20];               // anchor = (4q)/80
    float st = fast_sig(ct);
    float cv[4] = {c4.x, c4.y, c4.z, c4.w};
    #pragma unroll
    for (int j = 0; j < 4; ++j) {
      float s = sqrtf(fast_sig(cv[j]) * st);
      if (s >= prehi) {
        unsigned fb = __float_as_uint(s);
        unsigned bin = (fb - BIN_LO) >> BSHIFT;
        if (bin > NB-1) bin = NB-1;
        atomicAdd(&tl[bin], 1u);
        float ex = score_ref(cv[j], ct);  // exact, operands already in registers
        unsigned pos = atomicAdd(&pcnt, 1u);
        if (pos < PBUF_CAP)
          pbuf[pos] = ((ull)__float_as_uint(ex) << 32)
                    | (ull)(0xFFFFFFFFu - (unsigned)(4*q + j));
      }
    }
  }
  __syncthreads();
  unsigned n = pcnt;
  if (n > PBUF_CAP) { if (tid == 0) p.lvlbad[l] = 1u; n = PBUF_CAP; }
  if (tid == 0) base_sh = atomicAdd(&p.gcnt[l*16], n);
  __syncthreads();
  unsigned base = base_sh;
  ull* gc = p.gcand + (size_t)l * GCAP;
  for (unsigned i = tid; i < n; i += 256) {
    unsigned d = base + i;
    if (d < GCAP) gc[d] = pbuf[i];
    else p.lvlbad[l] = 1u;
  }
}

// Filter ONCE per level (8 slices x 256 thr): thr from suffix-scan, compact
// gcand -> ckey (order non-deterministic; keys unique so ranks invariant).
__global__ __launch_bounds__(256) void k_filter(Params p) {
  int bx = blockIdx.x;
  int l = bx >> 3, slice = bx & 7;
  int tid = threadIdx.x;
  __shared__ unsigned sfx[NB];
  __shared__ ull cbuf[CAND_CAP];
  __shared__ unsigned pcnt;
  __shared__ unsigned thr_sh;
  __shared__ unsigned base_sh;
  if (tid == 0) { pcnt = 0u; thr_sh = BIN_LO; }
  for (int j = tid; j < NB; j += 256) sfx[j] = p.tot[l*NB + j];
  __syncthreads();
  for (int off = 1; off < NB; off <<= 1) {
    unsigned v[4];
    #pragma unroll
    for (int j = 0; j < 4; ++j) {
      int idx = tid + j*256;
      unsigned add = (idx + off < NB) ? sfx[idx + off] : 0u;
      v[j] = sfx[idx] + add;
    }
    __syncthreads();
    #pragma unroll
    for (int j = 0; j < 4; ++j) sfx[tid + j*256] = v[j];
    __syncthreads();
  }
  unsigned k = (unsigned)d_KL[l];
  #pragma unroll
  for (int j = 0; j < 4; ++j) {
    int b = tid + j*256;
    unsigned s0 = sfx[b];
    unsigned s1 = (b + 1 < NB) ? sfx[b+1] : 0u;
    if (s0 >= k && (b == NB-1 || s1 < k))
      thr_sh = (b > 0) ? (BIN_LO + ((unsigned)(b-1) << BSHIFT)) : BIN_LO; // 1-bin safety
  }
  __syncthreads();
  unsigned thr = thr_sh;
  const float* cls = cls_of(p, l);
  const float* ctn = ctn_of(p, l);
  bool fastok = (p.lvlbad[l] == 0u) && (thr >= __float_as_uint(d_PREHI[l]));
  if (fastok) {
    int gn = (int)p.gcnt[l*16]; if (gn > GCAP) gn = GCAP;
    int chunk = (gn + 7) >> 3;
    int iA = slice * chunk, iB = iA + chunk;
    if (iA > gn) iA = gn;
    if (iB > gn) iB = gn;
    const ull* gc = p.gcand + (size_t)l * GCAP;
    for (int i = iA + tid; i < iB; i += 256) {
      ull kk = gc[i];
      if ((unsigned)(kk >> 32) >= thr) {
        unsigned pos = atomicAdd(&pcnt, 1u);
        if (pos < CAND_CAP) cbuf[pos] = kk;
      }
    }
  } else {
    // fallback: slice-partitioned full rescan, exact rescore on hits
    int ne = d_EL[l];
    int chunk = (ne + 7) >> 3;
    int eA = slice * chunk, eB = eA + chunk;
    if (eA > ne) eA = ne;
    if (eB > ne) eB = ne;
    for (int e = eA + tid; e < eB; e += 256) {
      float fs = fast_score(cls[e], ctn[e / NCLS]);
      if (__float_as_uint(fs) >= thr) {
        float ex = score_ref(cls[e], ctn[e / NCLS]);
        unsigned pos = atomicAdd(&pcnt, 1u);
        if (pos < CAND_CAP)
          cbuf[pos] = ((ull)__float_as_uint(ex) << 32)
                    | (ull)(0xFFFFFFFFu - (unsigned)e);
      }
    }
  }
  __syncthreads();
  unsigned n = pcnt; if (n > CAND_CAP) n = CAND_CAP;
  if (tid == 0) base_sh = atomicAdd(&p.ccount[l*16], n);
  __syncthreads();
  unsigned bp = base_sh;
  ull* ck = p.ckey + (size_t)l * CAND_CAP;
  for (unsigned i = tid; i < n; i += 256) {
    unsigned d = bp + i;
    if (d < CAND_CAP) ck[d] = cbuf[i];
  }
}

// Rank: 64 slice-waves per level from ckey; emits labels/boxes/slots + class lists
__global__ __launch_bounds__(64) void k_rank(Params p) {
  int bx = blockIdx.x;
  int l = bx >> 6, slice = bx & 63;
  int lane = threadIdx.x;
  int m = (int)p.ccount[l*16]; if (m > CAND_CAP) m = CAND_CAP;
  int kL = d_KL[l], obase = d_OB[l];
  int i = slice*64 + lane;
  if (slice*64 >= m) {
    if (i >= m && i < kL) {  // defensive fill (m >= kL in practice; out poisoned)
      int g = obase + i;
      p.out[g] = 0.0f;
      p.out[NTOT + g] = 0.0f;
      ((float4*)(p.out + 2*NTOT))[g] = make_float4(0,0,0,0);
      p.out[6*NTOT + g] = 0.0f;
      ((float4*)p.slot_box)[g] = make_float4(0,0,0,0);
      p.slot_bits[g] = 0u;
      p.slot_label[g] = 0xFFFFFFFFu;
    }
    return;
  }
  __shared__ ull key[CAND_CAP];
  const ull* ck = p.ckey + (size_t)l * CAND_CAP;
  for (int j = lane; j < m; j += 64) key[j] = ck[j];
  __syncthreads();
  if (i >= m) {
    if (i < kL) {
      int g = obase + i;
      p.out[g] = 0.0f;
      p.out[NTOT + g] = 0.0f;
      ((float4*)(p.out + 2*NTOT))[g] = make_float4(0,0,0,0);
      p.out[6*NTOT + g] = 0.0f;
      ((float4*)p.slot_box)[g] = make_float4(0,0,0,0);
      p.slot_bits[g] = 0u;
      p.slot_label[g] = 0xFFFFFFFFu;
    }
    return;
  }
  ull mine = key[i];
  int rank = 0;
  int mm = m & ~7;
  #pragma unroll 1
  for (int j = 0; j < mm; j += 8) {
    rank += (key[j  ] > mine) + (key[j+1] > mine) + (key[j+2] > mine) + (key[j+3] > mine)
          + (key[j+4] > mine) + (key[j+5] > mine) + (key[j+6] > mine) + (key[j+7] > mine);
  }
  for (int j = mm; j < m; ++j) rank += (key[j] > mine) ? 1 : 0;
  if (rank >= kL) return;
  int g = obase + rank;
  unsigned bits = (unsigned)(mine >> 32);
  unsigned fi = 0xFFFFFFFFu - (unsigned)(mine & 0xFFFFFFFFu);
  unsigned lab = fi % NCLS;
  unsigned a = fi / NCLS;
  float img = (float)(*p.img);
  float4 b4 = ((const float4*)box_of(p, l))[a];
  float4 nb;
  nb.x = fminf(fmaxf(b4.x / img, 0.0f), 1.0f);
  nb.y = fminf(fmaxf(b4.y / img, 0.0f), 1.0f);
  nb.z = fminf(fmaxf(b4.z / img, 0.0f), 1.0f);
  nb.w = fminf(fmaxf(b4.w / img, 0.0f), 1.0f);
  p.out[NTOT + g] = (float)lab;
  ((float4*)(p.out + 2*NTOT))[g] = nb;
  ((float4*)p.slot_box)[g] = b4;
  p.slot_bits[g] = bits;
  p.slot_label[g] = lab;
  unsigned pos = atomicAdd(&p.clscnt[lab*16], 1u);
  if (pos < CLS_CAP)
    p.clskey[lab*CLS_CAP + pos] = ((ull)bits << 32) | (ull)(0xFFFFFFFFu - (unsigned)g);
}

// Per-class NMS. m<=64: single-wave shfl/ballot path (no barriers).
__global__ __launch_bounds__(64) void k_nms(Params p) {
  int c = blockIdx.x, lane = threadIdx.x;
  int mc = (int)p.clscnt[c*16];
  if (mc == 0) return;
  if (mc <= 64) {
    ull kk = (lane < mc) ? p.clskey[c*CLS_CAP + lane] : 0ULL;
    int rank = 0;
    #pragma unroll 1
    for (int j = 0; j < 64; ++j) {
      ull kj = __shfl(kk, j);
      rank += (j < mc && kj > kk) ? 1 : 0;
    }
    __shared__ ull wkey[64];
    if (lane < mc) wkey[rank] = kk;
    __syncthreads();
    ull sk = (lane < mc) ? wkey[lane] : 0ULL;
    unsigned g = 0xFFFFFFFFu - (unsigned)(sk & 0xFFFFFFFFu);
    float s = __uint_as_float((unsigned)(sk >> 32));
    float off = 2.0f * (float)c;
    float x1=0,y1=0,x2=0,y2=0;
    if (lane < mc) {
      float4 b4 = ((const float4*)p.slot_box)[g];
      x1 = b4.x + off; y1 = b4.y + off; x2 = b4.z + off; y2 = b4.w + off;
    }
    ull keepm = __ballot(lane < mc && s > 0.05f);
    for (int i = 0; i + 1 < mc; ++i) {
      if ((keepm >> i) & 1ULL) {
        float ax1 = __shfl(x1, i), ay1 = __shfl(y1, i);
        float ax2 = __shfl(x2, i), ay2 = __shfl(y2, i);
        bool kept = (keepm >> lane) & 1ULL;
        bool sup = kept && (lane > i) && (lane < mc) &&
                   (iou_ref(ax1,ay1,ax2,ay2, x1,y1,x2,y2) > 0.6f);
        keepm &= ~__ballot(sup);
      }
    }
    if (lane < mc) {
      int kp = (int)((keepm >> lane) & 1ULL);
      p.out[g] = kp ? s : 0.0f;
      p.out[6*NTOT + g] = kp ? 1.0f : 0.0f;
    }
    return;
  }
  // LDS path (rare): 64<mc<=128 from clskey; mc>128 rebuild by scanning slots
  __shared__ ull key[NMS_CAP];
  __shared__ ull skey[NMS_CAP];
  __shared__ float bxs[NMS_CAP*4];
  __shared__ int keep[NMS_CAP];
  __shared__ unsigned mcnt_s;
  int m;
  if (mc <= CLS_CAP) {
    for (int j = lane; j < mc; j += 64) key[j] = p.clskey[c*CLS_CAP + j];
    m = mc;
    __syncthreads();
  } else {
    if (lane == 0) mcnt_s = 0u;
    __syncthreads();
    for (int g = lane; g < NTOT; g += 64) {
      if (p.slot_label[g] == (unsigned)c) {
        unsigned pos = atomicAdd(&mcnt_s, 1u);
        if (pos < NMS_CAP)
          key[pos] = ((ull)p.slot_bits[g] << 32) | (ull)(0xFFFFFFFFu - (unsigned)g);
      }
    }
    __syncthreads();
    m = (mcnt_s < NMS_CAP) ? (int)mcnt_s : NMS_CAP;
  }
  for (int i = lane; i < m; i += 64) {
    ull mine = key[i];
    int rank = 0;
    for (int j = 0; j < m; ++j) rank += (key[j] > mine) ? 1 : 0;
    skey[rank] = mine;
  }
  __syncthreads();
  float off = 2.0f * (float)c;
  for (int j = lane; j < m; j += 64) {
    ull kk = skey[j];
    unsigned g = 0xFFFFFFFFu - (unsigned)(kk & 0xFFFFFFFFu);
    for (int q = 0; q < 4; ++q) bxs[j*4+q] = p.slot_box[g*4+q] + off;
    float s = __uint_as_float((unsigned)(kk >> 32));
    keep[j] = (s > 0.05f) ? 1 : 0;
  }
  __syncthreads();
  for (int i = 0; i + 1 < m; ++i) {
    if (keep[i]) {
      float ax1 = bxs[i*4+0], ay1 = bxs[i*4+1], ax2 = bxs[i*4+2], ay2 = bxs[i*4+3];
      for (int j = i + 1 + lane; j < m; j += 64) {
        if (keep[j]) {
          if (iou_ref(ax1,ay1,ax2,ay2, bxs[j*4+0],bxs[j*4+1],bxs[j*4+2],bxs[j*4+3]) > 0.6f)
            keep[j] = 0;
        }
      }
    }
    __syncthreads();
  }
  for (int j = lane; j < m; j += 64) {
    ull kk = skey[j];
    unsigned g = 0xFFFFFFFFu - (unsigned)(kk & 0xFFFFFFFFu);
    float s = __uint_as_float((unsigned)(kk >> 32));
    int kp = keep[j];
    p.out[g] = kp ? s : 0.0f;
    p.out[6*NTOT + g] = kp ? 1.0f : 0.0f;
  }
}

extern "C" void kernel_launch(void* const* d_in, const int* in_sizes, int n_in,
                              void* d_out, int out_size, void* d_ws, size_t ws_size,
                              hipStream_t stream) {
  Params p;
  p.cls0 = (const float*)d_in[0];  p.ctn0 = (const float*)d_in[1];  p.box0 = (const float*)d_in[2];
  p.cls1 = (const float*)d_in[3];  p.ctn1 = (const float*)d_in[4];  p.box1 = (const float*)d_in[5];
  p.cls2 = (const float*)d_in[6];  p.ctn2 = (const float*)d_in[7];  p.box2 = (const float*)d_in[8];
  p.cls3 = (const float*)d_in[9];  p.ctn3 = (const float*)d_in[10]; p.box3 = (const float*)d_in[11];
  p.cls4 = (const float*)d_in[12]; p.ctn4 = (const float*)d_in[13]; p.box4 = (const float*)d_in[14];
  p.img  = (const int*)d_in[15];

  char* w = (char*)d_ws;
  // contiguous zero region: tot | gcnt | ccount | clscnt | lvlbad
  unsigned* zbase = (unsigned*)w;
  p.tot    = zbase;                          // 5120 words
  p.gcnt   = zbase + 5120;                   // 80
  p.ccount = zbase + 5120 + 80;              // 80
  p.clscnt = zbase + 5120 + 160;             // 1280
  p.lvlbad = zbase + 5120 + 160 + 1280;      // 16
  w += (size_t)ZWORDS*4;
  p.gcand = (ull*)w;           w += (size_t)5*GCAP*8;        // 2,621,440
  p.ckey  = (ull*)w;           w += (size_t)5*CAND_CAP*8;    // 163,840
  p.clskey = (ull*)w;          w += (size_t)NCLS*CLS_CAP*8;  // 81,920
  p.slot_bits  = (unsigned*)w; w += NTOT*4;
  p.slot_label = (unsigned*)w; w += NTOT*4;
  p.slot_box   = (float*)w;    w += NTOT*16;
  p.out = (float*)d_out;

  hipLaunchKernelGGL(k_zero,   dim3(1),    dim3(256), 0, stream, zbase);
  hipLaunchKernelGGL(k_score,  dim3(NBLK), dim3(256), 0, stream, p);
  hipLaunchKernelGGL(k_filter, dim3(40),   dim3(256), 0, stream, p);
  hipLaunchKernelGGL(k_rank,   dim3(5*64), dim3(64),  0, stream, p);
  hipLaunchKernelGGL(k_nms,    dim3(80),   dim3(64),  0, stream, p);
}